// Round 6
// baseline (1460.337 us; speedup 1.0000x reference)
//
#include <hip/hip_runtime.h>
#include <math.h>

typedef unsigned int   u32;
typedef unsigned long long u64;

#define BSZ     16
#define CCH     256
#define TT      768
#define PT      12
#define NPATCHN 64
#define FFD     256
#define NH      4
#define GRID    768        /* blk = pq*16 + b; pq = p + 12*q; 48 blocks per b */

/* ---- workspace float offsets ---- */
#define WS_ST0  0
#define WS_ST1  49152
#define WS_M    98304                        /* 256*4 */
#define WS_CM1  99328
#define WS_WM2  99584
#define WS_BM2  99840
#define WS_G2S  99844                        /* 256*12 */
#define WS_B2   102916
#define WS_A    105988
#define WS_CCF  105992
#define WS_BAR  106048                       /* int[16*64] */
#define WS_GW   107072                       /* [12][12][256] g1*INVSF*Wagg */
#define WS_CA   143936                       /* [12][256] b1-fold + bagg    */
#define WS_XT   147200                       /* [16][768][256] BN0-folded x, transposed */
#define WS_OB   (147200 + BSZ*TT*CCH)        /* [16][768][256] out buffer (t-major) */
#define WS_END  (WS_OB + BSZ*TT*CCH)

#define INVSF   0.9999950000374996f   /* 1/sqrt(1+1e-5) */

__device__ __forceinline__ float med3f(float a, float b, float c){
  return fmaxf(fminf(a,b), fminf(fmaxf(a,b), c));
}

__device__ __forceinline__ float gelu_exact(float v){
  return 0.5f * v * (1.0f + erff(v * 0.7071067811865475f));
}

/* gelu via erf(v/sqrt2)=v*R(v^2), 4-coeff Taylor: |err|<1.2e-4 for |v|<=1
   (C2 inputs are |u|~0.1-0.3; |u|>1 is a many-sigma event) */
__device__ __forceinline__ float gelu_poly(float v){
  float t = v * v;
  float r = -2.3746564e-03f;
  r = fmaf(r, t,  1.9947114e-02f);
  r = fmaf(r, t, -1.3298076e-01f);
  r = fmaf(r, t,  7.9788456e-01f);
  float a = 0.5f * v;
  return fmaf(a * v, r, a);
}

/* ------------ precompute: fold rank-1 structure into small tables ------------ */
__global__ __launch_bounds__(1024) void precompute_kernel(
    const float* __restrict__ gg1, const float* __restrict__ bb1,
    const float* __restrict__ gg2, const float* __restrict__ bb2,
    const float* __restrict__ Wagg, const float* __restrict__ bagg,
    const float* __restrict__ We,  const float* __restrict__ be,
    const float* __restrict__ Wq,  const float* __restrict__ bq,
    const float* __restrict__ Wk,  const float* __restrict__ bk,
    const float* __restrict__ Wv,  const float* __restrict__ bv,
    const float* __restrict__ Wm1, const float* __restrict__ bm1,
    const float* __restrict__ Wm2, const float* __restrict__ bm2,
    float* __restrict__ ws)
{
  __shared__ float We_s[FFD], be_s[FFD];
  __shared__ float wq_s[FFD], cq_s[FFD], wk_s[FFD], wv_s[FFD], cv_s[FFD];
  const int tid  = threadIdx.x;
  const int lane = tid & 63;
  const int w    = tid >> 6;   /* 16 waves */

  if (tid < FFD) { We_s[tid] = We[tid]; be_s[tid] = be[tid]; }
  if (tid < 16*64) ((int*)(ws + WS_BAR))[tid] = 0;   /* barrier counters */
  __syncthreads();

  for (int f = w; f < FFD; f += 16) {
    float aq=0.f, cqa=0.f, ak=0.f, av=0.f, cva=0.f;
    #pragma unroll
    for (int k2 = 0; k2 < 4; ++k2) {
      int j = lane + 64*k2;
      float wev = We_s[j], bev = be_s[j];
      float q1 = Wq[f*FFD + j]; aq += q1*wev; cqa += q1*bev;
      float k1 = Wk[f*FFD + j]; ak += k1*wev;
      float v1 = Wv[f*FFD + j]; av += v1*wev; cva += v1*bev;
    }
    for (int ofs = 1; ofs < 64; ofs <<= 1) {
      aq += __shfl_xor(aq, ofs);  cqa += __shfl_xor(cqa, ofs);
      ak += __shfl_xor(ak, ofs);
      av += __shfl_xor(av, ofs);  cva += __shfl_xor(cva, ofs);
    }
    if (lane == 0) {
      wq_s[f] = aq; cq_s[f] = cqa + bq[f];
      wk_s[f] = ak;
      wv_s[f] = av; cv_s[f] = cva + bv[f];
    }
  }
  __syncthreads();

  if (w < NH) {
    int f = w*64 + lane;
    float a  = wq_s[f]*wk_s[f];
    float cc = cq_s[f]*wk_s[f];
    for (int ofs = 1; ofs < 64; ofs <<= 1) { a += __shfl_xor(a, ofs); cc += __shfl_xor(cc, ofs); }
    if (lane == 0) { ws[WS_A + w] = a * 0.125f; ws[WS_CCF + w] = cc * 0.125f; }
  }

  for (int g = w; g < FFD; g += 16) {
    float mk0=0.f, mk1=0.f, mk2=0.f, mk3=0.f, ca=0.f;
    #pragma unroll
    for (int k2 = 0; k2 < 4; ++k2) {
      int j = lane + 64*k2;
      float wv1 = Wm1[g*FFD + j];
      float pm = wv1 * wv_s[j];
      if (k2 == 0) mk0 = pm; else if (k2 == 1) mk1 = pm; else if (k2 == 2) mk2 = pm; else mk3 = pm;
      ca += wv1 * cv_s[j];
    }
    for (int ofs = 1; ofs < 64; ofs <<= 1) {
      mk0 += __shfl_xor(mk0, ofs); mk1 += __shfl_xor(mk1, ofs);
      mk2 += __shfl_xor(mk2, ofs); mk3 += __shfl_xor(mk3, ofs);
      ca  += __shfl_xor(ca,  ofs);
    }
    if (lane == 0) {
      ws[WS_M + g*4 + 0] = mk0; ws[WS_M + g*4 + 1] = mk1;
      ws[WS_M + g*4 + 2] = mk2; ws[WS_M + g*4 + 3] = mk3;
      ws[WS_CM1 + g] = ca + bm1[g];
    }
  }

  if (tid < FFD)   ws[WS_WM2 + tid] = Wm2[tid];
  if (tid == 0)    ws[WS_BM2] = bm2[0];
  for (int i = tid; i < CCH*PT; i += 1024) {
    ws[WS_G2S + i] = gg2[i] * INVSF;  ws[WS_B2 + i] = bb2[i];
  }
  /* gw[p][j][c] = g1[c,j]*INVSF*Wagg[p,j] ; ca[p][c] = sum_j b1[c,j]*Wagg[p,j] + bagg[p] */
  for (int i = tid; i < PT*PT*CCH; i += 1024) {
    int p2  = i / (PT*CCH);
    int rem = i - p2*PT*CCH;
    int j   = rem / CCH;
    int c   = rem - j*CCH;
    ws[WS_GW + i] = gg1[c*PT + j] * INVSF * Wagg[p2*PT + j];
  }
  for (int i = tid; i < PT*CCH; i += 1024) {
    int p2 = i / CCH, c = i - p2*CCH;
    float s = 0.f;
    #pragma unroll
    for (int j = 0; j < PT; ++j) s += bb1[c*PT + j] * Wagg[p2*PT + j];
    ws[WS_CA + i] = s + bagg[p2];
  }
}

/* ------------ main: 768 blocks x 256 thr; 4 sub-blocks per (b,p) slice channels;
   per-b 48-block atomic barrier once per step; transposes fused ------------ */
__global__ __launch_bounds__(256, 4) void main_kernel(
    const float* __restrict__ x, const float* __restrict__ g0, const float* __restrict__ b0,
    float* __restrict__ ws, float* __restrict__ out, int big)
{
  const int blk = blockIdx.x;
  const int b   = blk & 15;          /* all 48 blocks of b: blk%8 = b%8 (XCD locality) */
  const int pq  = blk >> 4;          /* 0..47 */
  const int p   = pq % 12;
  const int q   = pq / 12;           /* channel slice [64q, 64q+64) */
  const int tid = threadIdx.x;

  __shared__ float gw_sh[PT][CCH];                        /* 12 KB */
  __shared__ float ca_sh[CCH];
  __shared__ __align__(16) float M_sh[(CCH + 16) * 4];    /* skewed: row g at g+g/16 */
  __shared__ __align__(8)  float cw_sh[(CCH + 16) * 2];
  __shared__ __align__(16) float S1_sh[NH][64];
  __shared__ float s_sh[CCH], res_sh[CCH];
  __shared__ float g2col_sh[CCH], b2col_sh[CCH];
  __shared__ __align__(16) float zp_sh[32][64];           /* doubles as 32x33 tile */
  __shared__ float zred_sh[4][64];
  __shared__ float a_sh[NH], c_sh[NH];
  __shared__ float tb_sh[8];

  int* bar = ((int*)(ws + WS_BAR)) + b * 64;
  int rnd = 0;
  float* tile = &zp_sh[0][0];

#define B_BARRIER() do { \
    __syncthreads(); \
    ++rnd; \
    if (tid == 0) { \
      __hip_atomic_fetch_add(bar, 1, __ATOMIC_RELEASE, __HIP_MEMORY_SCOPE_AGENT); \
      int tgt = 48 * rnd; \
      while (__hip_atomic_load(bar, __ATOMIC_RELAXED, __HIP_MEMORY_SCOPE_AGENT) < tgt) \
        __builtin_amdgcn_s_sleep(1); \
      __builtin_amdgcn_fence(__ATOMIC_ACQUIRE, "agent"); \
    } \
    __syncthreads(); \
  } while (0)

  /* ---- prologue: transpose 4 of this b's 192 x-tiles into XT (BN0 folded) ---- */
  if (big) {
    const int tx = tid & 31, ty = tid >> 5;   /* ty 0..7 */
    #pragma unroll
    for (int k = 0; k < 4; ++k) {
      int tau = pq*4 + k;
      int t0 = (tau % 24) * 32;
      int c0 = (tau / 24) * 32;
      __syncthreads();
      #pragma unroll
      for (int r = 0; r < 4; ++r) {
        int c = c0 + ty + r*8;
        int ict = c*TT + t0 + tx;
        tile[(ty + r*8)*33 + tx] = fmaf(x[b*CCH*TT + ict], g0[ict]*INVSF, b0[ict]);
      }
      __syncthreads();
      #pragma unroll
      for (int r = 0; r < 4; ++r) {
        int tt = t0 + ty + r*8;
        ws[WS_XT + (b*TT + tt)*CCH + c0 + tx] = tile[tx*33 + ty + r*8];
      }
    }
  }
  B_BARRIER();   /* round 1: XT of b complete */

  /* ---- load per-block LDS tables ---- */
  for (int i = tid; i < PT*CCH; i += 256) (&gw_sh[0][0])[i] = ws[WS_GW + p*PT*CCH + i];
  if (tid < CCH) {
    ca_sh[tid] = ws[WS_CA + p*CCH + tid];
    int g = tid, gs = g + (g >> 4);
    M_sh[gs*4+0] = ws[WS_M + g*4+0];
    M_sh[gs*4+1] = ws[WS_M + g*4+1];
    M_sh[gs*4+2] = ws[WS_M + g*4+2];
    M_sh[gs*4+3] = ws[WS_M + g*4+3];
    cw_sh[gs*2+0] = ws[WS_CM1 + g];
    cw_sh[gs*2+1] = ws[WS_WM2 + g];
    g2col_sh[tid] = ws[WS_G2S + tid*PT + p];
    b2col_sh[tid] = ws[WS_B2  + tid*PT + p];
  }
  if (tid < NH) { a_sh[tid] = ws[WS_A + tid]; c_sh[tid] = ws[WS_CCF + tid]; }
  const float bm2v = ws[WS_BM2];

  /* ---- t=0: state slice + output ---- */
  if (tid < 64) {
    int c = q*64 + tid;
    float xv;
    if (big) xv = ws[WS_XT + (b*TT + p)*CCH + c];
    else { int ict = c*TT + p; xv = fmaf(x[b*CCH*TT+ict], g0[ict]*INVSF, b0[ict]); }
    ws[WS_ST0 + (b*PT + p)*CCH + c] = xv;
    if (big) ws[WS_OB + (b*TT + p)*CCH + c] = xv;
    else     out[b*CCH*TT + c*TT + p] = xv;
  }
  B_BARRIER();   /* round 2: state t=0 visible */

  for (int t = 1; t < NPATCHN; ++t) {
    const float* stP = ws + ((t & 1) ? WS_ST0 : WS_ST1) + (b*PT)*CCH;
    float*       stN = ws + ((t & 1) ? WS_ST1 : WS_ST0) + (b*PT)*CCH;

    /* ---- phase A (duplicated x4): res + s for ALL 256 channels ---- */
    {
      const int c = tid;
      float acc = ca_sh[c];
      #pragma unroll
      for (int j = 0; j < PT; ++j)
        acc = fmaf(stP[j*CCH + c], gw_sh[j][c], acc);
      float inp = gelu_exact(acc);
      float xv;
      if (big) xv = ws[WS_XT + (b*TT + t*PT + p)*CCH + c];
      else { int ict = c*TT + t*PT + p; xv = fmaf(x[b*CCH*TT+ict], g0[ict]*INVSF, b0[ict]); }
      float res = inp + xv;
      res_sh[c] = res;
      s_sh[c] = fmaf(res, g2col_sh[c], b2col_sh[c]);
    }
    __syncthreads();

    /* ---- phase B: value-only top-3 (wave 0) / bottom-3 (wave 1) ---- */
    {
      const int wv = tid >> 6, lane = tid & 63;
      if (wv < 2) {
        float v0 = s_sh[lane], v1 = s_sh[lane+64], v2 = s_sh[lane+128], v3 = s_sh[lane+192];
        if (wv == 1) { v0 = -v0; v1 = -v1; v2 = -v2; v3 = -v3; }
        float h1 = fmaxf(v0,v1), l1 = fminf(v0,v1);
        float h2 = fmaxf(v2,v3), l2 = fminf(v2,v3);
        float y1 = fminf(h1,h2), x2 = fmaxf(l1,l2);
        float t1 = fmaxf(h1,h2);
        float t2 = fmaxf(y1,x2);
        float t3 = fminf(y1,x2);
        #pragma unroll
        for (int ofs = 1; ofs < 64; ofs <<= 1) {
          float o1 = __shfl_xor(t1, ofs), o2 = __shfl_xor(t2, ofs), o3 = __shfl_xor(t3, ofs);
          float yy = fminf(t1,o1), xx = fmaxf(t2,o2);
          float n1 = fmaxf(t1,o1);
          float n2 = fmaxf(yy,xx);
          float n3 = med3f(yy, xx, fmaxf(t3,o3));
          t1 = n1; t2 = n2; t3 = n3;
        }
        if (lane == 0) {
          if (wv == 0) { tb_sh[0] = t1; tb_sh[1] = t2; tb_sh[2] = t3; }
          else         { tb_sh[4] = -t1; tb_sh[5] = -t2; tb_sh[6] = -t3; }
        }
      }
    }
    __syncthreads();

    /* ---- phase C: S1[h][cl] for own 64-channel slice (64c x 4h threads) ---- */
    {
      const int h = tid >> 6, cl = tid & 63;
      float sval = s_sh[q*64 + cl];
      float tv0 = tb_sh[0], tv1 = tb_sh[1], tv2 = tb_sh[2];
      float bv0 = tb_sh[4], bv1 = tb_sh[5], bv2 = tb_sh[6];
      float alpha = fmaf(a_sh[h], sval, c_sh[h]);
      bool pos = alpha > 0.0f;
      float v1 = pos ? tv0 : bv0;
      float v2 = pos ? tv1 : bv1;
      float v3 = pos ? tv2 : bv2;
      float m  = alpha * v1;
      float e2 = __expf(fmaf(alpha, v2, -m));
      float e3 = __expf(fmaf(alpha, v3, -m));
      float num = fmaf(e2, v2, v1) + e3 * v3;
      float den = (1.0f + e2) + e3;
      float s1 = num / den;
      if (alpha == 0.0f) s1 = (s_sh[0] + s_sh[1] + s_sh[2]) * (1.0f/3.0f);
      S1_sh[h][cl] = s1;
    }
    __syncthreads();

    /* ---- phase C2: zpart[g-chunk][cl] ; 8 channels x 8 g per thread ---- */
    {
      const int cq = tid & 7, ch = tid >> 3;   /* cq: channel octet, ch: g-chunk 0..31 */
      const int c0 = cq * 8;
      const float4 sA0 = *(const float4*)&S1_sh[0][c0], sB0 = *(const float4*)&S1_sh[0][c0+4];
      const float4 sA1 = *(const float4*)&S1_sh[1][c0], sB1 = *(const float4*)&S1_sh[1][c0+4];
      const float4 sA2 = *(const float4*)&S1_sh[2][c0], sB2 = *(const float4*)&S1_sh[2][c0+4];
      const float4 sA3 = *(const float4*)&S1_sh[3][c0], sB3 = *(const float4*)&S1_sh[3][c0+4];
      float a0=0.f,a1=0.f,a2=0.f,a3=0.f,a4=0.f,a5=0.f,a6=0.f,a7=0.f;
      const int gb = ch * 8;
      #pragma unroll
      for (int i = 0; i < 8; ++i) {
        int g  = gb + i;
        int gs = g + (g >> 4);
        const float4 m4 = *(const float4*)&M_sh[gs*4];
        const float2 cw = *(const float2*)&cw_sh[gs*2];
        float u0 = fmaf(m4.x, sA0.x, cw.x); u0 = fmaf(m4.y, sA1.x, u0); u0 = fmaf(m4.z, sA2.x, u0); u0 = fmaf(m4.w, sA3.x, u0);
        float u1 = fmaf(m4.x, sA0.y, cw.x); u1 = fmaf(m4.y, sA1.y, u1); u1 = fmaf(m4.z, sA2.y, u1); u1 = fmaf(m4.w, sA3.y, u1);
        float u2 = fmaf(m4.x, sA0.z, cw.x); u2 = fmaf(m4.y, sA1.z, u2); u2 = fmaf(m4.z, sA2.z, u2); u2 = fmaf(m4.w, sA3.z, u2);
        float u3 = fmaf(m4.x, sA0.w, cw.x); u3 = fmaf(m4.y, sA1.w, u3); u3 = fmaf(m4.z, sA2.w, u3); u3 = fmaf(m4.w, sA3.w, u3);
        float u4 = fmaf(m4.x, sB0.x, cw.x); u4 = fmaf(m4.y, sB1.x, u4); u4 = fmaf(m4.z, sB2.x, u4); u4 = fmaf(m4.w, sB3.x, u4);
        float u5 = fmaf(m4.x, sB0.y, cw.x); u5 = fmaf(m4.y, sB1.y, u5); u5 = fmaf(m4.z, sB2.y, u5); u5 = fmaf(m4.w, sB3.y, u5);
        float u6 = fmaf(m4.x, sB0.z, cw.x); u6 = fmaf(m4.y, sB1.z, u6); u6 = fmaf(m4.z, sB2.z, u6); u6 = fmaf(m4.w, sB3.z, u6);
        float u7 = fmaf(m4.x, sB0.w, cw.x); u7 = fmaf(m4.y, sB1.w, u7); u7 = fmaf(m4.z, sB2.w, u7); u7 = fmaf(m4.w, sB3.w, u7);
        a0 = fmaf(cw.y, gelu_poly(u0), a0);
        a1 = fmaf(cw.y, gelu_poly(u1), a1);
        a2 = fmaf(cw.y, gelu_poly(u2), a2);
        a3 = fmaf(cw.y, gelu_poly(u3), a3);
        a4 = fmaf(cw.y, gelu_poly(u4), a4);
        a5 = fmaf(cw.y, gelu_poly(u5), a5);
        a6 = fmaf(cw.y, gelu_poly(u6), a6);
        a7 = fmaf(cw.y, gelu_poly(u7), a7);
      }
      *(float4*)&zp_sh[ch][c0]   = make_float4(a0, a1, a2, a3);
      *(float4*)&zp_sh[ch][c0+4] = make_float4(a4, a5, a6, a7);
    }
    __syncthreads();

    /* ---- phase D: two-stage reduce over 32 g-chunks; write state + out ---- */
    {
      const int cl = tid & 63, kk = tid >> 6;
      float sum = 0.f;
      #pragma unroll
      for (int m2 = 0; m2 < 8; ++m2) sum += zp_sh[kk*8 + m2][cl];
      zred_sh[kk][cl] = sum;
    }
    __syncthreads();
    if (tid < 64) {
      float z = ((zred_sh[0][tid] + zred_sh[1][tid]) + (zred_sh[2][tid] + zred_sh[3][tid])) + bm2v;
      int c = q*64 + tid;
      float nw = fmaf(0.5f, z, res_sh[c]);
      stN[p*CCH + c] = nw;
      if (big) ws[WS_OB + (b*TT + t*PT + p)*CCH + c] = nw;
      else     out[b*CCH*TT + c*TT + t*PT + p] = nw;
    }
    if (t < NPATCHN-1) B_BARRIER();   /* rounds 3..64 */
  }

  /* ---- epilogue: transpose 4 of this b's OB tiles to out ---- */
  if (big) {
    B_BARRIER();   /* OB of b complete */
    const int tx = tid & 31, ty = tid >> 5;
    #pragma unroll
    for (int k = 0; k < 4; ++k) {
      int tau = pq*4 + k;
      int t0 = (tau % 24) * 32;
      int c0 = (tau / 24) * 32;
      __syncthreads();
      #pragma unroll
      for (int r = 0; r < 4; ++r) {
        int tt = t0 + ty + r*8;
        tile[(ty + r*8)*33 + tx] = ws[WS_OB + (b*TT + tt)*CCH + c0 + tx];
      }
      __syncthreads();
      #pragma unroll
      for (int r = 0; r < 4; ++r) {
        int c = c0 + ty + r*8;
        out[b*CCH*TT + c*TT + t0 + tx] = tile[tx*33 + ty + r*8];
      }
    }
  }
#undef B_BARRIER
}

extern "C" void kernel_launch(void* const* d_in, const int* in_sizes, int n_in,
                              void* d_out, int out_size, void* d_ws, size_t ws_size,
                              hipStream_t stream) {
  (void)in_sizes; (void)n_in; (void)out_size;
  const float* x    = (const float*)d_in[0];
  const float* g0   = (const float*)d_in[1];
  const float* b0   = (const float*)d_in[2];
  const float* gg1  = (const float*)d_in[3];
  const float* bb1  = (const float*)d_in[4];
  const float* gg2  = (const float*)d_in[5];
  const float* bb2  = (const float*)d_in[6];
  const float* Wagg = (const float*)d_in[7];
  const float* bagg = (const float*)d_in[8];
  const float* We   = (const float*)d_in[9];
  const float* be   = (const float*)d_in[10];
  const float* Wq   = (const float*)d_in[11];
  const float* bq   = (const float*)d_in[12];
  const float* Wk   = (const float*)d_in[13];
  const float* bk   = (const float*)d_in[14];
  const float* Wv   = (const float*)d_in[15];
  const float* bv   = (const float*)d_in[16];
  const float* Wm1  = (const float*)d_in[17];
  const float* bm1  = (const float*)d_in[18];
  const float* Wm2  = (const float*)d_in[19];
  const float* bm2  = (const float*)d_in[20];
  float* ws  = (float*)d_ws;
  float* out = (float*)d_out;

  int big = (ws_size >= (size_t)WS_END * sizeof(float)) ? 1 : 0;

  hipLaunchKernelGGL(precompute_kernel, dim3(1), dim3(1024), 0, stream,
                     gg1, bb1, gg2, bb2, Wagg, bagg, We, be,
                     Wq, bq, Wk, bk, Wv, bv, Wm1, bm1, Wm2, bm2, ws);

  hipLaunchKernelGGL(main_kernel, dim3(GRID), dim3(256), 0, stream,
                     x, g0, b0, ws, out, big);
}

// Round 7
// 542.847 us; speedup vs baseline: 2.6901x; 2.6901x over previous
//
#include <hip/hip_runtime.h>
#include <math.h>

typedef unsigned int   u32;
typedef unsigned long long u64;

#define BSZ     16
#define CCH     256
#define TT      768
#define PT      12
#define NPATCHN 64
#define FFD     256
#define NH      4
#define GRID    (BSZ*PT)   /* 192 blocks x 1024 thr; blk = p*16 + b */

/* ---- workspace float offsets ---- */
#define WS_ST0  0
#define WS_ST1  49152
#define WS_M    98304                        /* 256*4 */
#define WS_CM1  99328
#define WS_WM2  99584
#define WS_BM2  99840
#define WS_G2S  99844                        /* 256*12 */
#define WS_B2   102916
#define WS_A    105988
#define WS_CCF  105992
#define WS_BAR  106048                       /* int[16*64] */
#define WS_GW   107072                       /* [12][12][256] g1*INVSF*Wagg */
#define WS_CA   143936                       /* [12][256] b1-fold + bagg    */
#define WS_XT   147200                       /* [16][768][256] BN0-folded x, transposed */
#define WS_END  (WS_XT + BSZ*TT*CCH)

#define INVSF   0.9999950000374996f   /* 1/sqrt(1+1e-5) */

__device__ __forceinline__ float med3f(float a, float b, float c){
  return fmaxf(fminf(a,b), fminf(fmaxf(a,b), c));
}

__device__ __forceinline__ float gelu_exact(float v){
  return 0.5f * v * (1.0f + erff(v * 0.7071067811865475f));
}

/* gelu via erf(v/sqrt2)=v*R(v^2), 4-coeff Taylor: |err|<1.2e-4 for |v|<=1
   (C2 inputs are |u|~0.1-0.3) */
__device__ __forceinline__ float gelu_poly(float v){
  float t = v * v;
  float r = -2.3746564e-03f;
  r = fmaf(r, t,  1.9947114e-02f);
  r = fmaf(r, t, -1.3298076e-01f);
  r = fmaf(r, t,  7.9788456e-01f);
  float a = 0.5f * v;
  return fmaf(a * v, r, a);
}

/* L3-coherent (cross-XCD safe) payload accessors: sc0+sc1, no fences */
__device__ __forceinline__ float aload(const float* p){
  return __hip_atomic_load(p, __ATOMIC_RELAXED, __HIP_MEMORY_SCOPE_AGENT);
}
__device__ __forceinline__ void astore(float* p, float v){
  __hip_atomic_store(p, v, __ATOMIC_RELAXED, __HIP_MEMORY_SCOPE_AGENT);
}

/* ------------ precompute: fold rank-1 structure into small tables ------------ */
__global__ __launch_bounds__(1024) void precompute_kernel(
    const float* __restrict__ gg1, const float* __restrict__ bb1,
    const float* __restrict__ gg2, const float* __restrict__ bb2,
    const float* __restrict__ Wagg, const float* __restrict__ bagg,
    const float* __restrict__ We,  const float* __restrict__ be,
    const float* __restrict__ Wq,  const float* __restrict__ bq,
    const float* __restrict__ Wk,  const float* __restrict__ bk,
    const float* __restrict__ Wv,  const float* __restrict__ bv,
    const float* __restrict__ Wm1, const float* __restrict__ bm1,
    const float* __restrict__ Wm2, const float* __restrict__ bm2,
    float* __restrict__ ws)
{
  __shared__ float We_s[FFD], be_s[FFD];
  __shared__ float wq_s[FFD], cq_s[FFD], wk_s[FFD], wv_s[FFD], cv_s[FFD];
  const int tid  = threadIdx.x;
  const int lane = tid & 63;
  const int w    = tid >> 6;   /* 16 waves */

  if (tid < FFD) { We_s[tid] = We[tid]; be_s[tid] = be[tid]; }
  if (tid < 16*64) ((int*)(ws + WS_BAR))[tid] = 0;   /* barrier counters */
  __syncthreads();

  for (int f = w; f < FFD; f += 16) {
    float aq=0.f, cqa=0.f, ak=0.f, av=0.f, cva=0.f;
    #pragma unroll
    for (int k2 = 0; k2 < 4; ++k2) {
      int j = lane + 64*k2;
      float wev = We_s[j], bev = be_s[j];
      float q1 = Wq[f*FFD + j]; aq += q1*wev; cqa += q1*bev;
      float k1 = Wk[f*FFD + j]; ak += k1*wev;
      float v1 = Wv[f*FFD + j]; av += v1*wev; cva += v1*bev;
    }
    for (int ofs = 1; ofs < 64; ofs <<= 1) {
      aq += __shfl_xor(aq, ofs);  cqa += __shfl_xor(cqa, ofs);
      ak += __shfl_xor(ak, ofs);
      av += __shfl_xor(av, ofs);  cva += __shfl_xor(cva, ofs);
    }
    if (lane == 0) {
      wq_s[f] = aq; cq_s[f] = cqa + bq[f];
      wk_s[f] = ak;
      wv_s[f] = av; cv_s[f] = cva + bv[f];
    }
  }
  __syncthreads();

  if (w < NH) {
    int f = w*64 + lane;
    float a  = wq_s[f]*wk_s[f];
    float cc = cq_s[f]*wk_s[f];
    for (int ofs = 1; ofs < 64; ofs <<= 1) { a += __shfl_xor(a, ofs); cc += __shfl_xor(cc, ofs); }
    if (lane == 0) { ws[WS_A + w] = a * 0.125f; ws[WS_CCF + w] = cc * 0.125f; }
  }

  for (int g = w; g < FFD; g += 16) {
    float mk0=0.f, mk1=0.f, mk2=0.f, mk3=0.f, ca=0.f;
    #pragma unroll
    for (int k2 = 0; k2 < 4; ++k2) {
      int j = lane + 64*k2;
      float wv1 = Wm1[g*FFD + j];
      float pm = wv1 * wv_s[j];
      if (k2 == 0) mk0 = pm; else if (k2 == 1) mk1 = pm; else if (k2 == 2) mk2 = pm; else mk3 = pm;
      ca += wv1 * cv_s[j];
    }
    for (int ofs = 1; ofs < 64; ofs <<= 1) {
      mk0 += __shfl_xor(mk0, ofs); mk1 += __shfl_xor(mk1, ofs);
      mk2 += __shfl_xor(mk2, ofs); mk3 += __shfl_xor(mk3, ofs);
      ca  += __shfl_xor(ca,  ofs);
    }
    if (lane == 0) {
      ws[WS_M + g*4 + 0] = mk0; ws[WS_M + g*4 + 1] = mk1;
      ws[WS_M + g*4 + 2] = mk2; ws[WS_M + g*4 + 3] = mk3;
      ws[WS_CM1 + g] = ca + bm1[g];
    }
  }

  if (tid < FFD)   ws[WS_WM2 + tid] = Wm2[tid];
  if (tid == 0)    ws[WS_BM2] = bm2[0];
  for (int i = tid; i < CCH*PT; i += 1024) {
    ws[WS_G2S + i] = gg2[i] * INVSF;  ws[WS_B2 + i] = bb2[i];
  }
  /* gw[p][j][c] = g1[c,j]*INVSF*Wagg[p,j] ; ca[p][c] = sum_j b1[c,j]*Wagg[p,j] + bagg[p] */
  for (int i = tid; i < PT*PT*CCH; i += 1024) {
    int p2  = i / (PT*CCH);
    int rem = i - p2*PT*CCH;
    int j   = rem / CCH;
    int c   = rem - j*CCH;
    ws[WS_GW + i] = gg1[c*PT + j] * INVSF * Wagg[p2*PT + j];
  }
  for (int i = tid; i < PT*CCH; i += 1024) {
    int p2 = i / CCH, c = i - p2*CCH;
    float s = 0.f;
    #pragma unroll
    for (int j = 0; j < PT; ++j) s += bb1[c*PT + j] * Wagg[p2*PT + j];
    ws[WS_CA + i] = s + bagg[p2];
  }
}

/* ------------ main: 192 blocks x 1024 thr; per-b 12-block relaxed barrier;
   state exchanged via L3 (sc0sc1 atomics) — no per-step cache flushes ------------ */
__global__ __launch_bounds__(1024) void main_kernel(
    const float* __restrict__ x, const float* __restrict__ g0, const float* __restrict__ b0,
    float* __restrict__ ws, float* __restrict__ out, int big)
{
  const int blk = blockIdx.x;
  const int b   = blk & 15;
  const int p   = blk >> 4;          /* 0..11 */
  const int tid = threadIdx.x;

  __shared__ float gw_sh[PT][CCH];                        /* 12 KB */
  __shared__ float ca_sh[CCH];
  __shared__ __align__(16) float M_sh[CCH*4];             /* broadcast reads in C2 */
  __shared__ __align__(8)  float cw_sh[CCH*2];
  __shared__ __align__(16) float S1_sh[NH][CCH];
  __shared__ float s_sh[CCH];
  __shared__ float g2col_sh[CCH], b2col_sh[CCH];
  __shared__ __align__(16) float zp_sh[4][1056];          /* 16.5KB: 4x(32x33) tiles | [16][256] zpart */
  __shared__ float a_sh[NH], c_sh[NH];
  __shared__ float tb_sh[8];

  float (*zpart)[CCH] = (float (*)[CCH])&zp_sh[0][0];
  int* bar = ((int*)(ws + WS_BAR)) + b * 64;
  int rnd = 0;

  /* ---- prologue: transpose this b's 16 x-tiles (4 groups x 4 tiles) into XT ---- */
  if (big) {
    const int grp = tid >> 8;            /* 0..3 */
    const int tx  = tid & 31;
    const int ty  = (tid >> 5) & 7;      /* 0..7 */
    float* tl = &zp_sh[grp][0];
    #pragma unroll
    for (int k = 0; k < 4; ++k) {
      int tau = p*16 + k*4 + grp;        /* 0..191 */
      int t0 = (tau % 24) * 32;
      int c0 = (tau / 24) * 32;
      __syncthreads();
      #pragma unroll
      for (int r = 0; r < 4; ++r) {
        int c = c0 + ty + r*8;
        int ict = c*TT + t0 + tx;
        tl[(ty + r*8)*33 + tx] = fmaf(x[b*CCH*TT + ict], g0[ict]*INVSF, b0[ict]);
      }
      __syncthreads();
      #pragma unroll
      for (int r = 0; r < 4; ++r) {
        int tt = t0 + ty + r*8;
        ws[WS_XT + (b*TT + tt)*CCH + c0 + tx] = tl[tx*33 + ty + r*8];
      }
    }
  }
  /* heavy one-time barrier: release/acquire so XT becomes plainly-cacheable */
  __syncthreads();
  ++rnd;
  if (tid == 0) {
    __hip_atomic_fetch_add(bar, 1, __ATOMIC_RELEASE, __HIP_MEMORY_SCOPE_AGENT);
    while (__hip_atomic_load(bar, __ATOMIC_RELAXED, __HIP_MEMORY_SCOPE_AGENT) < 12*rnd)
      __builtin_amdgcn_s_sleep(1);
    __builtin_amdgcn_fence(__ATOMIC_ACQUIRE, "agent");
  }
  __syncthreads();

  /* ---- per-block LDS tables ---- */
  for (int i = tid; i < PT*CCH; i += 1024) (&gw_sh[0][0])[i] = ws[WS_GW + p*PT*CCH + i];
  if (tid < CCH) {
    ca_sh[tid] = ws[WS_CA + p*CCH + tid];
    M_sh[tid*4+0] = ws[WS_M + tid*4+0];
    M_sh[tid*4+1] = ws[WS_M + tid*4+1];
    M_sh[tid*4+2] = ws[WS_M + tid*4+2];
    M_sh[tid*4+3] = ws[WS_M + tid*4+3];
    cw_sh[tid*2+0] = ws[WS_CM1 + tid];
    cw_sh[tid*2+1] = ws[WS_WM2 + tid];
    g2col_sh[tid] = ws[WS_G2S + tid*PT + p];
    b2col_sh[tid] = ws[WS_B2  + tid*PT + p];
  }
  if (tid < NH) { a_sh[tid] = ws[WS_A + tid]; c_sh[tid] = ws[WS_CCF + tid]; }
  const float bm2v = ws[WS_BM2];

  /* ---- t=0: state row p via L3 stores; out direct ---- */
  if (tid < CCH) {
    float xv;
    if (big) xv = ws[WS_XT + (b*TT + p)*CCH + tid];
    else { int ict = tid*TT + p; xv = fmaf(x[b*CCH*TT+ict], g0[ict]*INVSF, b0[ict]); }
    astore(ws + WS_ST0 + (b*PT + p)*CCH + tid, xv);
    out[b*CCH*TT + tid*TT + p] = xv;
  }
  /* light barrier (round 2): syncthreads drains vmcnt -> sc1 stores are at L3 */
  __syncthreads();
  ++rnd;
  if (tid == 0) {
    __hip_atomic_fetch_add(bar, 1, __ATOMIC_RELAXED, __HIP_MEMORY_SCOPE_AGENT);
    while (__hip_atomic_load(bar, __ATOMIC_RELAXED, __HIP_MEMORY_SCOPE_AGENT) < 12*rnd)
      __builtin_amdgcn_s_sleep(1);
  }
  __syncthreads();

  float res = 0.f;

  for (int t = 1; t < NPATCHN; ++t) {
    float* stP = ws + ((t & 1) ? WS_ST0 : WS_ST1) + (b*PT)*CCH;
    float* stN = ws + ((t & 1) ? WS_ST1 : WS_ST0) + (b*PT)*CCH;

    /* ---- phase A: 12 L3 state loads + fold + gelu + residual; s = BN2(res) ---- */
    if (tid < CCH) {
      const int c = tid;
      float sj[PT];
      #pragma unroll
      for (int j = 0; j < PT; ++j) sj[j] = aload(stP + j*CCH + c);
      float acc = ca_sh[c];
      #pragma unroll
      for (int j = 0; j < PT; ++j) acc = fmaf(sj[j], gw_sh[j][c], acc);
      float inp = gelu_exact(acc);
      float xv;
      if (big) xv = ws[WS_XT + (b*TT + t*PT + p)*CCH + c];
      else { int ict = c*TT + t*PT + p; xv = fmaf(x[b*CCH*TT+ict], g0[ict]*INVSF, b0[ict]); }
      res = inp + xv;
      s_sh[c] = fmaf(res, g2col_sh[c], b2col_sh[c]);
    }
    __syncthreads();

    /* ---- phase B: value-only top-3 (wave 0) / bottom-3 (wave 1) ---- */
    {
      const int wv = tid >> 6, lane = tid & 63;
      if (wv < 2) {
        float v0 = s_sh[lane], v1 = s_sh[lane+64], v2 = s_sh[lane+128], v3 = s_sh[lane+192];
        if (wv == 1) { v0 = -v0; v1 = -v1; v2 = -v2; v3 = -v3; }
        float h1 = fmaxf(v0,v1), l1 = fminf(v0,v1);
        float h2 = fmaxf(v2,v3), l2 = fminf(v2,v3);
        float y1 = fminf(h1,h2), x2 = fmaxf(l1,l2);
        float t1 = fmaxf(h1,h2);
        float t2 = fmaxf(y1,x2);
        float t3 = fminf(y1,x2);
        #pragma unroll
        for (int ofs = 1; ofs < 64; ofs <<= 1) {
          float o1 = __shfl_xor(t1, ofs), o2 = __shfl_xor(t2, ofs), o3 = __shfl_xor(t3, ofs);
          float yy = fminf(t1,o1), xx = fmaxf(t2,o2);
          float n1 = fmaxf(t1,o1);
          float n2 = fmaxf(yy,xx);
          float n3 = med3f(yy, xx, fmaxf(t3,o3));
          t1 = n1; t2 = n2; t3 = n3;
        }
        if (lane == 0) {
          if (wv == 0) { tb_sh[0] = t1; tb_sh[1] = t2; tb_sh[2] = t3; }
          else         { tb_sh[4] = -t1; tb_sh[5] = -t2; tb_sh[6] = -t3; }
        }
      }
    }
    __syncthreads();

    /* ---- phase C: S1[h][c], one (h,c) per thread ---- */
    {
      const int h = tid >> 8, c = tid & 255;
      float sval = s_sh[c];
      float tv0 = tb_sh[0], tv1 = tb_sh[1], tv2 = tb_sh[2];
      float bv0 = tb_sh[4], bv1 = tb_sh[5], bv2 = tb_sh[6];
      float alpha = fmaf(a_sh[h], sval, c_sh[h]);
      bool pos = alpha > 0.0f;
      float v1 = pos ? tv0 : bv0;
      float v2 = pos ? tv1 : bv1;
      float v3 = pos ? tv2 : bv2;
      float m  = alpha * v1;
      float e2 = __expf(fmaf(alpha, v2, -m));
      float e3 = __expf(fmaf(alpha, v3, -m));
      float num = fmaf(e2, v2, v1) + e3 * v3;
      float den = (1.0f + e2) + e3;
      float s1 = num / den;
      if (alpha == 0.0f) s1 = (s_sh[0] + s_sh[1] + s_sh[2]) * (1.0f/3.0f);
      S1_sh[h][c] = s1;
    }
    __syncthreads();

    /* ---- phase C2: 4 channels x 16 g per thread; M broadcast reads ---- */
    {
      const int quad = tid & 63;
      const int qq   = tid >> 6;      /* 16 g-groups of 16 */
      const int c0   = quad * 4;
      const float4 s0 = *(const float4*)&S1_sh[0][c0];
      const float4 s1 = *(const float4*)&S1_sh[1][c0];
      const float4 s2 = *(const float4*)&S1_sh[2][c0];
      const float4 s3 = *(const float4*)&S1_sh[3][c0];
      float a0=0.f, a1=0.f, a2=0.f, a3=0.f;
      const int gb = qq * 16;
      #pragma unroll 4
      for (int g = 0; g < 16; ++g) {
        const float4 m4 = *(const float4*)&M_sh[(gb + g)*4];
        const float2 cw = *(const float2*)&cw_sh[(gb + g)*2];
        float u0 = fmaf(m4.x, s0.x, cw.x); u0 = fmaf(m4.y, s1.x, u0); u0 = fmaf(m4.z, s2.x, u0); u0 = fmaf(m4.w, s3.x, u0);
        float u1 = fmaf(m4.x, s0.y, cw.x); u1 = fmaf(m4.y, s1.y, u1); u1 = fmaf(m4.z, s2.y, u1); u1 = fmaf(m4.w, s3.y, u1);
        float u2 = fmaf(m4.x, s0.z, cw.x); u2 = fmaf(m4.y, s1.z, u2); u2 = fmaf(m4.z, s2.z, u2); u2 = fmaf(m4.w, s3.z, u2);
        float u3 = fmaf(m4.x, s0.w, cw.x); u3 = fmaf(m4.y, s1.w, u3); u3 = fmaf(m4.z, s2.w, u3); u3 = fmaf(m4.w, s3.w, u3);
        a0 = fmaf(cw.y, gelu_poly(u0), a0);
        a1 = fmaf(cw.y, gelu_poly(u1), a1);
        a2 = fmaf(cw.y, gelu_poly(u2), a2);
        a3 = fmaf(cw.y, gelu_poly(u3), a3);
      }
      *(float4*)&zpart[qq][c0] = make_float4(a0, a1, a2, a3);
    }
    __syncthreads();

    /* ---- phase D: reduce 16 partials; state via L3 store; out direct ---- */
    if (tid < CCH) {
      float z = 0.f;
      #pragma unroll
      for (int qq = 0; qq < 16; ++qq) z += zpart[qq][tid];
      z += bm2v;
      float nw = fmaf(0.5f, z, res);
      astore(stN + p*CCH + tid, nw);
      out[b*CCH*TT + tid*TT + t*PT + p] = nw;
    }

    if (t < NPATCHN-1) {
      __syncthreads();   /* drains vmcnt: sc1 state stores reach L3 before arrive */
      ++rnd;
      if (tid == 0) {
        __hip_atomic_fetch_add(bar, 1, __ATOMIC_RELAXED, __HIP_MEMORY_SCOPE_AGENT);
        while (__hip_atomic_load(bar, __ATOMIC_RELAXED, __HIP_MEMORY_SCOPE_AGENT) < 12*rnd)
          __builtin_amdgcn_s_sleep(1);
      }
      __syncthreads();
    }
  }
}

extern "C" void kernel_launch(void* const* d_in, const int* in_sizes, int n_in,
                              void* d_out, int out_size, void* d_ws, size_t ws_size,
                              hipStream_t stream) {
  (void)in_sizes; (void)n_in; (void)out_size;
  const float* x    = (const float*)d_in[0];
  const float* g0   = (const float*)d_in[1];
  const float* b0   = (const float*)d_in[2];
  const float* gg1  = (const float*)d_in[3];
  const float* bb1  = (const float*)d_in[4];
  const float* gg2  = (const float*)d_in[5];
  const float* bb2  = (const float*)d_in[6];
  const float* Wagg = (const float*)d_in[7];
  const float* bagg = (const float*)d_in[8];
  const float* We   = (const float*)d_in[9];
  const float* be   = (const float*)d_in[10];
  const float* Wq   = (const float*)d_in[11];
  const float* bq   = (const float*)d_in[12];
  const float* Wk   = (const float*)d_in[13];
  const float* bk   = (const float*)d_in[14];
  const float* Wv   = (const float*)d_in[15];
  const float* bv   = (const float*)d_in[16];
  const float* Wm1  = (const float*)d_in[17];
  const float* bm1  = (const float*)d_in[18];
  const float* Wm2  = (const float*)d_in[19];
  const float* bm2  = (const float*)d_in[20];
  float* ws  = (float*)d_ws;
  float* out = (float*)d_out;

  int big = (ws_size >= (size_t)WS_END * sizeof(float)) ? 1 : 0;

  hipLaunchKernelGGL(precompute_kernel, dim3(1), dim3(1024), 0, stream,
                     gg1, bb1, gg2, bb2, Wagg, bagg, We, be,
                     Wq, bq, Wk, bk, Wv, bv, Wm1, bm1, Wm2, bm2, ws);

  hipLaunchKernelGGL(main_kernel, dim3(GRID), dim3(1024), 0, stream,
                     x, g0, b0, ws, out, big);
}